// Round 13
// baseline (165.263 us; speedup 1.0000x reference)
//
#include <hip/hip_runtime.h>
#include <hip/hip_bf16.h>

// CategorySpecificLinear: out[b,t,h] = sum_d x[b,t,d]*W[cat[b],d,h] + b[cat[b],h]
// R13: global_load_lds staging (fp32 raw into LDS, convert at fragment read)
// with per-wave COUNTED s_waitcnt vmcnt(N) — the compiler cannot insert
// dependency waits because gload_lds has no destination register. Padded LDS
// rows (X 144B=9 chunks, W 272B=17 chunks) keep gload_lds linear-dest AND give
// bank-floor reads. W repacked fp32->bf16 [n][k] in LDS per step (LDK=40,
// aligned b128). cat->XCD LPT so each cat's W is L2-resident on one XCD.

#define NCAT 32
#define DIN  1024
#define DH   1024
#define NBATCH 256
#define TT   32

#define NSLOT 64                 // record slots per XCD
#define NRECTOT (8 * NSLOT)      // 512
#define RSTRIDE 8                // cat, nb, b0..b3, pad2

#define BM 128
#define BN 64
#define BK 32
#define NITER (DIN / BK)         // 32
#define NTILES (DH / BN)         // 16

#define XROWF 36                 // f32 per X32 row (144B = 9 x 16B chunks)
#define WROWF 68                 // f32 per W32 row (272B = 17 x 16B chunks)
#define XBUFF (BM * XROWF)       // 4608 f32 (18 KB); 18 gload instrs exactly
#define WBUFF 2304               // 9 gload instrs x 256 f32 (row data 32*68=2176)
#define LDKW 40                  // wt row stride in shorts (80B, 16B-aligned)

typedef __attribute__((ext_vector_type(4))) float f32x4;
typedef __attribute__((ext_vector_type(8))) short bf16x8;

__device__ __forceinline__ short f2bf(float f) {
    __hip_bfloat16 h = __float2bfloat16(f);
    return __builtin_bit_cast(short, h);
}

// ---------------------------------------------------------------------------
// Setup: per-cat 4-batch records; cats LPT-assigned to XCD arenas (slot space
// [x*NSLOT, x*NSLOT+NSLOT)) so all records+ntiles of a cat run on one XCD.
// ---------------------------------------------------------------------------
__global__ void cat_setup_kernel(const int* __restrict__ cat_ids,
                                 int* __restrict__ recs) {
    __shared__ int cats[NBATCH];
    __shared__ int cnt[NCAT];
    __shared__ int slotstart[NCAT];
    __shared__ int order[NCAT];
    const int t = threadIdx.x;
    cats[t] = cat_ids[t];
    for (int i = t; i < NRECTOT * RSTRIDE; i += 256) recs[i] = 0;
    __syncthreads();
    if (t < NCAT) {
        int c = 0;
        for (int i = 0; i < NBATCH; ++i) c += (cats[i] == t) ? 1 : 0;
        cnt[t] = c;
    }
    __syncthreads();
    if (t == 0) {
        for (int c = 0; c < NCAT; ++c) order[c] = c;
        for (int i = 0; i < NCAT; ++i) {          // selection sort by cnt desc
            int best = i;
            for (int k = i + 1; k < NCAT; ++k)
                if (cnt[order[k]] > cnt[order[best]]) best = k;
            int tmp = order[i]; order[i] = order[best]; order[best] = tmp;
        }
        int load[8]  = {0,0,0,0,0,0,0,0};
        int nexts[8];
        for (int x2 = 0; x2 < 8; ++x2) nexts[x2] = x2 * NSLOT;
        for (int i = 0; i < NCAT; ++i) {          // LPT greedy
            int c = order[i];
            int nr = (cnt[c] + 3) >> 2;
            if (nr == 0) { slotstart[c] = -1; continue; }
            int bx = 0;
            for (int x2 = 1; x2 < 8; ++x2) if (load[x2] < load[bx]) bx = x2;
            slotstart[c] = nexts[bx];
            nexts[bx] += nr;
            load[bx]  += nr;
        }
    }
    __syncthreads();
    if (t < NCAT && cnt[t] > 0) {
        int s = slotstart[t];
        int bidx[4];
        int nb = 0, k = 0;
        for (int i = 0; i < NBATCH; ++i) {
            if (cats[i] == t) {
                bidx[nb++] = i;
                if (nb == 4) {
                    int* r = recs + (s + k) * RSTRIDE;
                    r[0] = t; r[1] = 4;
                    r[2] = bidx[0]; r[3] = bidx[1]; r[4] = bidx[2]; r[5] = bidx[3];
                    ++k; nb = 0;
                }
            }
        }
        if (nb > 0) {
            int* r = recs + (s + k) * RSTRIDE;
            r[0] = t; r[1] = nb;
            r[2] = bidx[0];
            r[3] = (nb > 1) ? bidx[1] : bidx[0];
            r[4] = (nb > 2) ? bidx[2] : bidx[0];
            r[5] = (nb > 3) ? bidx[3] : bidx[0];
        }
    }
}

// ---------------------------------------------------------------------------
// GEMM: 256 threads = 4 waves (2m x 2n), wave tile 64x32, BM=128/BN=64/BK=32.
// Staging: 27 gload_lds(16B) instrs per K-step per block (18 X + 9 W), waves
// get {7,7,7,6}. Double-buffered fp32 LDS, one stage always in flight.
// ---------------------------------------------------------------------------
__global__ __launch_bounds__(256, 2)
void cat_gemm_kernel(const float* __restrict__ x,
                     const float* __restrict__ W,
                     const float* __restrict__ bias,
                     const int* __restrict__ recs,
                     float* __restrict__ out) {
    const int wg   = blockIdx.x;
    const int xcd  = wg & 7;
    const int idx  = wg >> 3;          // 0..1023
    const int nt   = idx & 15;         // ntile
    const int s    = idx >> 4;         // slot 0..63
    const int* rec = recs + (xcd * NSLOT + s) * RSTRIDE;
    const int cat  = rec[0];
    const int nb   = rec[1];
    if (nb == 0) return;
    const int n0 = nt * BN;

    __shared__ float xs32[2][XBUFF];   // 2 x 18 KB
    __shared__ float ws32[2][WBUFF];   // 2 x 9 KB
    __shared__ short wt[BN * LDKW];    // 5 KB (bf16 [n][k], rebuilt per step)

    const int t    = threadIdx.x;
    const int lane = t & 63;
    const int w    = t >> 6;           // wave 0..3
    const int wm   = w >> 1;           // 0..1
    const int wn   = w & 1;            // 0..1
    const int fl   = lane & 15;
    const int kb   = lane >> 4;

    // ---- staging map precompute (per wave: up to 7 instrs) ----
    const float* sbase[7];
    int sstep[7], sdoff[7];
    bool sisx[7], svalid[7];
#pragma unroll
    for (int jj = 0; jj < 7; ++jj) {
        const int j = w * 7 + jj;
        svalid[jj] = (j < 27);
        sbase[jj] = x; sstep[jj] = 0; sdoff[jj] = 0; sisx[jj] = true;
        if (j < 18) {                          // X instr: 1KB = rows of 144B
            int g = j * 64 + lane;             // chunk id 0..1151
            int row = g / 9, c = g % 9;
            if (c == 8) c = 0;                 // pad chunk: harmless dup source
            int slot = row >> 5, trow = row & 31;
            sbase[jj] = x + (size_t)(rec[2 + slot] * TT + trow) * DIN + c * 4;
            sstep[jj] = BK;                    // f32 per K-step
            sdoff[jj] = j * 256;               // f32 offset in xs32 buf
            sisx[jj]  = true;
        } else if (j < 27) {                   // W instr: rows of 272B
            int g = (j - 18) * 64 + lane;      // chunk id 0..575
            int row = g / 17, c = g % 17;
            if (c == 16) c = 0;                // pad chunk
            if (row > 31) row = 31;            // tail pad instrs: dup source
            sbase[jj] = W + (size_t)cat * (DIN * DH) + (size_t)row * DH + n0 + c * 4;
            sstep[jj] = BK * DH;
            sdoff[jj] = (j - 18) * 256;
            sisx[jj]  = false;
        }
    }

    // W repack assignment: thread -> k-rows {k2,k2+1}, n cols n4..n4+3
    const int wk2 = (t & 15) * 2;
    const int wn4 = (t >> 4) * 4;

    float bv[2];
#pragma unroll
    for (int ni = 0; ni < 2; ++ni)
        bv[ni] = bias[cat * DH + n0 + wn * 32 + ni * 16 + fl];

    f32x4 acc[4][2];
#pragma unroll
    for (int i = 0; i < 4; ++i)
#pragma unroll
        for (int q = 0; q < 2; ++q)
            acc[i][q] = (f32x4){0.f, 0.f, 0.f, 0.f};

    // ---- stage issuer: 16B gload_lds per valid instr ----
    auto STAGE = [&](int it2) {
        float* xb = &xs32[it2 & 1][0];
        float* wb = &ws32[it2 & 1][0];
#pragma unroll
        for (int jj = 0; jj < 7; ++jj) {
            if (svalid[jj]) {
                const float* src = sbase[jj] + (size_t)it2 * sstep[jj];
                float* dst = (sisx[jj] ? xb : wb) + sdoff[jj];
                __builtin_amdgcn_global_load_lds(
                    (const __attribute__((address_space(1))) void*)src,
                    (__attribute__((address_space(3))) void*)dst, 16, 0, 0);
            }
        }
    };

    // prologue: stages 0 and 1 in flight
    STAGE(0);
    STAGE(1);

    for (int it = 0; it < NITER; ++it) {
        const int buf = it & 1;

        // (a) wait for THIS wave's stage-it gloads (stage it+1 stays in flight)
        if (it == NITER - 1) {
            asm volatile("s_waitcnt vmcnt(0)" ::: "memory");
        } else if (w == 3) {
            asm volatile("s_waitcnt vmcnt(6)" ::: "memory");
        } else {
            asm volatile("s_waitcnt vmcnt(7)" ::: "memory");
        }
        __builtin_amdgcn_sched_barrier(0);
        // (b) block-wide: everyone's stage-it contribution has landed
        __builtin_amdgcn_s_barrier();
        asm volatile("" ::: "memory");

        // (c) repack W32[buf] (fp32 [k][n]) -> wt (bf16 [n][k])
        {
            const float* wr = &ws32[buf][0] + wk2 * WROWF + wn4;
            f32x4 v0 = *(const f32x4*)wr;
            f32x4 v1 = *(const f32x4*)(wr + WROWF);
#pragma unroll
            for (int q = 0; q < 4; ++q) {
                unsigned pk = (unsigned)(unsigned short)f2bf(v0[q]) |
                              ((unsigned)(unsigned short)f2bf(v1[q]) << 16);
                *(unsigned*)(&wt[(wn4 + q) * LDKW + wk2]) = pk;
            }
        }

        // (d) A fragments: read fp32 rows from xs32[buf], convert to bf16
        bf16x8 af[4];
#pragma unroll
        for (int mi = 0; mi < 4; ++mi) {
            const float* ar = &xs32[buf][0] + (wm * 64 + mi * 16 + fl) * XROWF + kb * 8;
            f32x4 lo = *(const f32x4*)ar;
            f32x4 hi = *(const f32x4*)(ar + 4);
            bf16x8 fr;
            fr[0] = f2bf(lo[0]); fr[1] = f2bf(lo[1]);
            fr[2] = f2bf(lo[2]); fr[3] = f2bf(lo[3]);
            fr[4] = f2bf(hi[0]); fr[5] = f2bf(hi[1]);
            fr[6] = f2bf(hi[2]); fr[7] = f2bf(hi[3]);
            af[mi] = fr;
        }

        // (e) wt writes + all reads of buf complete block-wide
        asm volatile("s_waitcnt lgkmcnt(0)" ::: "memory");
        __builtin_amdgcn_s_barrier();
        asm volatile("" ::: "memory");

        // (f) issue stage it+2 into buf (safe: all reads of buf done by (e))
        if (it + 2 < NITER) STAGE(it + 2);

        // (g) B fragments from wt + MFMA
        bf16x8 bfr[2];
#pragma unroll
        for (int ni = 0; ni < 2; ++ni)
            bfr[ni] = *(const bf16x8*)(&wt[(wn * 32 + ni * 16 + fl) * LDKW + kb * 8]);

        __builtin_amdgcn_s_setprio(1);
#pragma unroll
        for (int mi = 0; mi < 4; ++mi)
#pragma unroll
            for (int ni = 0; ni < 2; ++ni)
                acc[mi][ni] = __builtin_amdgcn_mfma_f32_16x16x32_bf16(
                    af[mi], bfr[ni], acc[mi][ni], 0, 0, 0);
        __builtin_amdgcn_s_setprio(0);
    }

    // ---- epilogue: bias + store rows of real batch slots ----
#pragma unroll
    for (int mi = 0; mi < 4; ++mi) {
        const int slot = wm * 2 + (mi >> 1);
        if (slot < nb) {
            const int batch = rec[2 + slot];
            const int rb = (mi & 1) * 16 + kb * 4;
#pragma unroll
            for (int jj = 0; jj < 4; ++jj) {
                const int trow = rb + jj;
                float* orow = out + (size_t)(batch * TT + trow) * DH + n0 + wn * 32;
#pragma unroll
                for (int ni = 0; ni < 2; ++ni)
                    orow[ni * 16 + fl] = acc[mi][ni][jj] + bv[ni];
            }
        }
    }
}

extern "C" void kernel_launch(void* const* d_in, const int* in_sizes, int n_in,
                              void* d_out, int out_size, void* d_ws, size_t ws_size,
                              hipStream_t stream) {
    const float* x       = (const float*)d_in[0];
    const int*   cat_ids = (const int*)d_in[1];
    const float* W       = (const float*)d_in[2];
    const float* bias    = (const float*)d_in[3];
    float*       out     = (float*)d_out;
    int*         recs    = (int*)d_ws;

    hipLaunchKernelGGL(cat_setup_kernel, dim3(1), dim3(256), 0, stream,
                       cat_ids, recs);
    // grid: 8 XCD arenas x 64 slots x 16 ntiles; empty slots exit immediately
    hipLaunchKernelGGL(cat_gemm_kernel, dim3(NRECTOT * NTILES), dim3(256),
                       0, stream, x, W, bias, recs, out);
}

// Round 14
// 146.252 us; speedup vs baseline: 1.1300x; 1.1300x over previous
//
#include <hip/hip_runtime.h>
#include <hip/hip_bf16.h>

// CategorySpecificLinear: out[b,t,h] = sum_d x[b,t,d]*W[cat[b],d,h] + b[cat[b],h]
// R14: 4-batch records (BM=128), BN=128, 256-thr 4-wave blocks (wave tile
// 64x64), LDS 40KB -> 3 independent blocks/CU (m114 cross-block overlap).
// ~704 active blocks <= 768 resident capacity -> single generation, no tail.
// LPT record deal across XCD arenas. Unconditional staging (dup slot0),
// distance-1 reg prefetch, raw s_barrier lgkm-only drain, setprio on MFMA.

#define NCAT 32
#define DIN  1024
#define DH   1024
#define NBATCH 256
#define TT   32

#define NSLOT 64                 // record slots per XCD arena (worst case)
#define NRECTOT (8 * NSLOT)      // 512
#define RSTRIDE 8                // cat, nb, b0..b3, pad2

#define BM 128
#define BN 128
#define BK 32
#define LDK 40                   // LDS row stride (shorts): 80B, 16B-aligned
#define NITER (DIN / BK)         // 32
#define NTILES (DH / BN)         // 8

typedef __attribute__((ext_vector_type(4))) float f32x4;
typedef __attribute__((ext_vector_type(8))) short bf16x8;
typedef __attribute__((ext_vector_type(4))) short bf16x4;

__device__ __forceinline__ short f2bf(float f) {
    __hip_bfloat16 h = __float2bfloat16(f);
    return __builtin_bit_cast(short, h);
}

// ---------------------------------------------------------------------------
// Setup: per-cat 4-batch records, LPT-assigned to XCD arenas so each XCD gets
// ~equal record load and a cat's records+ntiles share one XCD's L2.
// ---------------------------------------------------------------------------
__global__ void cat_setup_kernel(const int* __restrict__ cat_ids,
                                 int* __restrict__ recs) {
    __shared__ int cats[NBATCH];
    __shared__ int cnt[NCAT];
    __shared__ int slotstart[NCAT];
    __shared__ int order[NCAT];
    const int t = threadIdx.x;
    cats[t] = cat_ids[t];
    for (int i = t; i < NRECTOT * RSTRIDE; i += 256) recs[i] = 0;
    __syncthreads();
    if (t < NCAT) {
        int c = 0;
        for (int i = 0; i < NBATCH; ++i) c += (cats[i] == t) ? 1 : 0;
        cnt[t] = c;
    }
    __syncthreads();
    if (t == 0) {
        for (int c = 0; c < NCAT; ++c) order[c] = c;
        for (int i = 0; i < NCAT; ++i) {          // selection sort by cnt desc
            int best = i;
            for (int k = i + 1; k < NCAT; ++k)
                if (cnt[order[k]] > cnt[order[best]]) best = k;
            int tmp = order[i]; order[i] = order[best]; order[best] = tmp;
        }
        int load[8] = {0,0,0,0,0,0,0,0};
        int nexts[8];
        for (int a = 0; a < 8; ++a) nexts[a] = a * NSLOT;
        for (int i = 0; i < NCAT; ++i) {          // LPT greedy
            int c = order[i];
            int nr = (cnt[c] + 3) >> 2;
            if (nr == 0) { slotstart[c] = -1; continue; }
            int bx = 0;
            for (int a = 1; a < 8; ++a) if (load[a] < load[bx]) bx = a;
            slotstart[c] = nexts[bx];
            nexts[bx] += nr;
            load[bx]  += nr;
        }
    }
    __syncthreads();
    if (t < NCAT && cnt[t] > 0) {
        int s = slotstart[t];
        int bidx[4];
        int nb = 0, k = 0;
        for (int i = 0; i < NBATCH; ++i) {
            if (cats[i] == t) {
                bidx[nb++] = i;
                if (nb == 4) {
                    int* r = recs + (s + k) * RSTRIDE;
                    r[0] = t; r[1] = 4;
                    r[2] = bidx[0]; r[3] = bidx[1]; r[4] = bidx[2]; r[5] = bidx[3];
                    ++k; nb = 0;
                }
            }
        }
        if (nb > 0) {
            int* r = recs + (s + k) * RSTRIDE;
            r[0] = t; r[1] = nb;
            r[2] = bidx[0];
            r[3] = (nb > 1) ? bidx[1] : bidx[0];
            r[4] = (nb > 2) ? bidx[2] : bidx[0];
            r[5] = (nb > 3) ? bidx[3] : bidx[0];
        }
    }
}

// One K-step: convert+stage tile it (unconditional), prefetch tile it+1 into
// the same regs, lgkm-only drain + s_barrier, fragments + 16 MFMA.
__device__ __forceinline__ void gemm_step(
    f32x4 (&xv)[4], f32x4 (&wv)[4],
    short* xd, short* wd,
    const short* ap, const short* bp,
    const float* xsrc, const float* wsrc,
    int wn4, int wk4, int it,
    f32x4 (&acc)[4][4]) {

    // X: row xr, 16 k-elems -> 2 bf16x8 LDS writes
    bf16x8 p0, p1;
#pragma unroll
    for (int q = 0; q < 4; ++q) {
        p0[q]     = f2bf(xv[0][q]);
        p0[q + 4] = f2bf(xv[1][q]);
        p1[q]     = f2bf(xv[2][q]);
        p1[q + 4] = f2bf(xv[3][q]);
    }
    *(bf16x8*)(xd)     = p0;
    *(bf16x8*)(xd + 8) = p1;

    // W: 4x4 register transpose -> 4 b64 writes wt[n][k]
#pragma unroll
    for (int j = 0; j < 4; ++j) {
        bf16x4 q;
        q[0] = f2bf(wv[0][j]);
        q[1] = f2bf(wv[1][j]);
        q[2] = f2bf(wv[2][j]);
        q[3] = f2bf(wv[3][j]);
        *(bf16x4*)(wd + (wn4 + j) * LDK + wk4) = q;
    }

    // prefetch tile it+1 into the just-freed registers (unconditional)
    if (it + 1 < NITER) {
        const int k0 = (it + 1) * BK;
#pragma unroll
        for (int q = 0; q < 4; ++q)
            xv[q] = *(const f32x4*)(xsrc + k0 + q * 4);
#pragma unroll
        for (int i = 0; i < 4; ++i)
            wv[i] = *(const f32x4*)(wsrc + (size_t)(k0 + i) * DH);
    }

    // drain LDS writes only — prefetch loads stay in flight across the barrier
    asm volatile("s_waitcnt lgkmcnt(0)" ::: "memory");
    __builtin_amdgcn_s_barrier();
    asm volatile("" ::: "memory");

    // fragments + MFMA on tile `it`
    bf16x8 af[4], bfr[4];
#pragma unroll
    for (int mi = 0; mi < 4; ++mi)
        af[mi] = *(const bf16x8*)(ap + mi * 16 * LDK);
#pragma unroll
    for (int ni = 0; ni < 4; ++ni)
        bfr[ni] = *(const bf16x8*)(bp + ni * 16 * LDK);

    __builtin_amdgcn_s_setprio(1);
#pragma unroll
    for (int mi = 0; mi < 4; ++mi)
#pragma unroll
        for (int ni = 0; ni < 4; ++ni)
            acc[mi][ni] = __builtin_amdgcn_mfma_f32_16x16x32_bf16(
                af[mi], bfr[ni], acc[mi][ni], 0, 0, 0);
    __builtin_amdgcn_s_setprio(0);
    // next step writes the other LDS buffer; reuse two steps ahead is ordered
    // by the next barrier's preceding lgkmcnt(0).
}

// ---------------------------------------------------------------------------
// Grouped GEMM. 256 threads = 4 waves (2m x 2n), wave tile 64x64.
// wg -> (xcd arena, slot, ntile); all 8 ntiles of a record on one XCD.
// ---------------------------------------------------------------------------
__global__ __launch_bounds__(256, 3)
void cat_gemm_kernel(const float* __restrict__ x,
                     const float* __restrict__ W,
                     const float* __restrict__ bias,
                     const int* __restrict__ recs,
                     float* __restrict__ out) {
    const int wg  = blockIdx.x;
    const int xcd = wg & 7;
    const int idx = wg >> 3;            // 0..511
    const int nt  = idx & 7;            // ntile
    const int s   = idx >> 3;           // slot 0..63
    const int* rec = recs + (xcd * NSLOT + s) * RSTRIDE;
    const int cat = rec[0];
    const int nb  = rec[1];
    if (nb == 0) return;
    const int n0 = nt * BN;

    __shared__ short xs[2][BM * LDK];   // 20 KB
    __shared__ short wt[2][BN * LDK];   // 20 KB  (total 40 KB -> 3 blocks/CU)

    const int t    = threadIdx.x;
    const int lane = t & 63;
    const int w    = t >> 6;     // wave 0..3
    const int wm   = w >> 1;     // 0..1
    const int wn   = w & 1;      // 0..1
    const int fl   = lane & 15;
    const int kb   = lane >> 4;

    // X staging: thread t -> tile row xr = t>>1 (0..127), k-half (t&1)*16.
    // Per wave-instr: 32 rows x 128B contiguous — fully coalesced.
    const int xr = t >> 1;
    const int xh = (t & 1) * 16;
    const int xbatch = rec[2 + (xr >> 5)];   // padded slots duplicate slot 0
    const float* xsrc = x + (size_t)(xbatch * TT + (xr & 31)) * DIN + xh;
    short* xd0 = &xs[0][0] + xr * LDK + xh;
    short* xd1 = &xs[1][0] + xr * LDK + xh;

    // W staging: k rows wk4..+3, n cols wn4..+3 (4x4 register transpose)
    const int wk4 = (t & 7) * 4;
    const int wn4 = (t >> 3) * 4;            // 0..124
    const float* wsrc = W + (size_t)cat * (DIN * DH) + (size_t)wk4 * DH + n0 + wn4;

    float bv[4];
#pragma unroll
    for (int ni = 0; ni < 4; ++ni)
        bv[ni] = bias[cat * DH + n0 + wn * 64 + ni * 16 + fl];

    f32x4 acc[4][4];
#pragma unroll
    for (int i = 0; i < 4; ++i)
#pragma unroll
        for (int q = 0; q < 4; ++q)
            acc[i][q] = (f32x4){0.f, 0.f, 0.f, 0.f};

    const short* ap0 = &xs[0][0] + (wm * 64 + fl) * LDK + kb * 8;
    const short* ap1 = &xs[1][0] + (wm * 64 + fl) * LDK + kb * 8;
    const short* bp0 = &wt[0][0] + (wn * 64 + fl) * LDK + kb * 8;
    const short* bp1 = &wt[1][0] + (wn * 64 + fl) * LDK + kb * 8;

    // prologue: load K-tile 0 (unconditional)
    f32x4 xv[4], wv[4];
#pragma unroll
    for (int q = 0; q < 4; ++q)
        xv[q] = *(const f32x4*)(xsrc + q * 4);
#pragma unroll
    for (int i = 0; i < 4; ++i)
        wv[i] = *(const f32x4*)(wsrc + (size_t)i * DH);

    for (int it = 0; it < NITER; it += 2) {
        gemm_step(xv, wv, xd0, &wt[0][0], ap0, bp0,
                  xsrc, wsrc, wn4, wk4, it, acc);
        gemm_step(xv, wv, xd1, &wt[1][0], ap1, bp1,
                  xsrc, wsrc, wn4, wk4, it + 1, acc);
    }

    // epilogue: bias + store rows of real batch slots only
#pragma unroll
    for (int mi = 0; mi < 4; ++mi) {
        const int slot = wm * 2 + (mi >> 1);
        if (slot < nb) {
            const int batch = rec[2 + slot];
            const int rb = (mi & 1) * 16 + kb * 4;
#pragma unroll
            for (int jj = 0; jj < 4; ++jj) {
                const int trow = rb + jj;
                float* orow = out + (size_t)(batch * TT + trow) * DH + n0 + wn * 64;
#pragma unroll
                for (int ni = 0; ni < 4; ++ni)
                    orow[ni * 16 + fl] = acc[mi][ni][jj] + bv[ni];
            }
        }
    }
}

extern "C" void kernel_launch(void* const* d_in, const int* in_sizes, int n_in,
                              void* d_out, int out_size, void* d_ws, size_t ws_size,
                              hipStream_t stream) {
    const float* x       = (const float*)d_in[0];
    const int*   cat_ids = (const int*)d_in[1];
    const float* W       = (const float*)d_in[2];
    const float* bias    = (const float*)d_in[3];
    float*       out     = (float*)d_out;
    int*         recs    = (int*)d_ws;

    hipLaunchKernelGGL(cat_setup_kernel, dim3(1), dim3(256), 0, stream,
                       cat_ids, recs);
    // grid: 8 arenas x 64 slots x 8 ntiles = 4096; empty slots exit instantly
    hipLaunchKernelGGL(cat_gemm_kernel, dim3(8 * NSLOT * NTILES), dim3(256),
                       0, stream, x, W, bias, recs, out);
}

// Round 15
// 83.103 us; speedup vs baseline: 1.9887x; 1.7599x over previous
//
#include <hip/hip_runtime.h>
#include <hip/hip_bf16.h>

// CategorySpecificLinear: out[b,t,h] = sum_d x[b,t,d] * W[cat[b],d,h] + bias[cat[b],h]
// B=256, T=32, D=1024, H=1024, NCAT=32.
// R15 = R7 restored (session best: 82 µs). One record per category (<=16
// batches, BM=512), BN=64, 1024-thread 16-wave blocks. W read ~once from L3
// (136 MB vs 350 for 4-batch records — byte volume, not schedule, is what the
// 14-round plateau tracked). Record's 16 ntiles on one XCD (X L2-shared).
// Desc-count sort + round-robin XCD deal for balance. Per-wave predicates skip
// staging/MFMA for empty batch slots. Distance-1 register prefetch +
// double-buffered LDS + raw s_barrier (lgkm-only drain).

#define NCAT 32
#define DIN  1024
#define DH   1024
#define NBATCH 256
#define TT   32
#define NRECPAD 48     // record slots (multiple of 8); sum ceil(cnt/16) <= 48
#define RSTRIDE 20     // ints per record: cat, nb, b0..b15, pad2

#define BM 512
#define BN 64
#define BK 32
#define LDK 40         // LDS row stride in bf16 elems (BK + 8 pad)
#define NITER (DIN / BK)   // 32
#define NTILES (DH / BN)   // 16

typedef __attribute__((ext_vector_type(4))) float f32x4;
typedef __attribute__((ext_vector_type(8))) short bf16x8;
typedef __attribute__((ext_vector_type(4))) short bf16x4;

__device__ inline short f2bf(float f) {
    unsigned u = __builtin_bit_cast(unsigned, f);
    u += 0x7fffu + ((u >> 16) & 1u);
    return (short)(u >> 16);
}

// ---------------------------------------------------------------------------
// Setup: group batches by category into records of <=16 batches, sort records
// by count desc (stable), write to recs[rank]. Rank r runs on XCD r%8.
// ---------------------------------------------------------------------------
__global__ void cat_setup_kernel(const int* __restrict__ cat_ids,
                                 int* __restrict__ recs) {
    __shared__ int cats[NBATCH];
    __shared__ int cnt[NCAT];
    __shared__ int off[NCAT + 1];
    __shared__ int rstart[NCAT + 1];
    __shared__ int blist[NBATCH];
    __shared__ int cbuf[NRECPAD * RSTRIDE];
    __shared__ int nrec_s;
    const int t = threadIdx.x;
    cats[t] = cat_ids[t];
    for (int i = t; i < NRECPAD * RSTRIDE; i += 256) cbuf[i] = 0;
    __syncthreads();
    if (t < NCAT) {
        int c = 0;
        for (int i = 0; i < NBATCH; ++i) c += (cats[i] == t) ? 1 : 0;
        cnt[t] = c;
    }
    __syncthreads();
    if (t == 0) {
        off[0] = 0; rstart[0] = 0;
        for (int c = 0; c < NCAT; ++c) {
            off[c + 1] = off[c] + cnt[c];
            rstart[c + 1] = rstart[c] + (cnt[c] + 15) / 16;
        }
        nrec_s = rstart[NCAT];
    }
    __syncthreads();
    {   // stable scatter: batches grouped by cat
        int c = cats[t], rank = 0;
        for (int i = 0; i < t; ++i) rank += (cats[i] == c) ? 1 : 0;
        blist[off[c] + rank] = t;
    }
    __syncthreads();
    if (t < NCAT) {   // build this cat's records
        int base = off[t], rem = cnt[t], k = 0;
        while (rem > 0) {
            int nb = rem < 16 ? rem : 16;
            int* rb = cbuf + (rstart[t] + k) * RSTRIDE;
            rb[0] = t; rb[1] = nb;
            for (int i = 0; i < nb; ++i) rb[2 + i] = blist[base + i];
            for (int i = nb; i < 16; ++i) rb[2 + i] = rb[2];
            base += nb; rem -= nb; ++k;
        }
    }
    __syncthreads();
    for (int i = t; i < NRECPAD * RSTRIDE; i += 256) recs[i] = 0;
    __syncthreads();
    const int nrec = nrec_s;
    if (t < nrec) {   // rank by nb desc (stable), write
        const int mynb = cbuf[t * RSTRIDE + 1];
        int rank = 0;
        for (int i = 0; i < nrec; ++i) {
            const int nbi = cbuf[i * RSTRIDE + 1];
            rank += ((nbi > mynb) || (nbi == mynb && i < t)) ? 1 : 0;
        }
        for (int f = 0; f < RSTRIDE; ++f)
            recs[rank * RSTRIDE + f] = cbuf[t * RSTRIDE + f];
    }
}

// One K-step: convert+stage tile it (predicated), prefetch tile it+1 into the
// same regs, barrier (lgkm-only drain), fragments + 8 MFMA (predicated).
__device__ __forceinline__ void gemm_step(
    f32x4 (&xv)[4], f32x4 (&wv)[4],
    short* xd, short* wd,
    const short* ap, const short* bp,
    const float* xsrc, const float* wsrc,
    bool xact, bool wact, bool mact,
    int wn4, int wk4, int it,
    f32x4 (&acc)[4][2]) {

    if (xact) {
#pragma unroll
        for (int i = 0; i < 4; ++i) {
            bf16x4 q;
            q[0] = f2bf(xv[i][0]);
            q[1] = f2bf(xv[i][1]);
            q[2] = f2bf(xv[i][2]);
            q[3] = f2bf(xv[i][3]);
            *(bf16x4*)(xd + i * 8 * LDK) = q;
        }
    }
    if (wact) {
#pragma unroll
        for (int j = 0; j < 4; ++j) {
            bf16x4 q;
            q[0] = f2bf(wv[0][j]);
            q[1] = f2bf(wv[1][j]);
            q[2] = f2bf(wv[2][j]);
            q[3] = f2bf(wv[3][j]);
            *(bf16x4*)(wd + (wn4 + j) * LDK + wk4) = q;
        }
    }

    if (it + 1 < NITER) {
        const int k0 = (it + 1) * BK;
        if (xact) {
#pragma unroll
            for (int i = 0; i < 4; ++i)
                xv[i] = *(const f32x4*)(xsrc + k0 + (size_t)(i * 8) * DIN);
        }
        if (wact) {
#pragma unroll
            for (int i = 0; i < 4; ++i)
                wv[i] = *(const f32x4*)(wsrc + (size_t)(k0 + i) * DH);
        }
    }

    asm volatile("s_waitcnt lgkmcnt(0)" ::: "memory");
    __builtin_amdgcn_s_barrier();
    asm volatile("" ::: "memory");

    if (mact) {
        bf16x8 af[4], bfr[2];
#pragma unroll
        for (int mi = 0; mi < 4; ++mi)
            af[mi] = *(const bf16x8*)(ap + mi * 16 * LDK);
#pragma unroll
        for (int ni = 0; ni < 2; ++ni)
            bfr[ni] = *(const bf16x8*)(bp + ni * 16 * LDK);
#pragma unroll
        for (int mi = 0; mi < 4; ++mi)
#pragma unroll
            for (int ni = 0; ni < 2; ++ni)
                acc[mi][ni] = __builtin_amdgcn_mfma_f32_16x16x32_bf16(
                    af[mi], bfr[ni], acc[mi][ni], 0, 0, 0);
    }
}

// ---------------------------------------------------------------------------
// Grouped GEMM. 1024 threads = 16 waves (8m x 2n), wave tile 64x32.
// wg -> (record rank r, ntile j) with all 16 ntiles of r on XCD r%8.
// ---------------------------------------------------------------------------
__global__ __launch_bounds__(1024)
void cat_gemm_kernel(const float* __restrict__ x,
                     const float* __restrict__ W,
                     const float* __restrict__ bias,
                     const int* __restrict__ recs,
                     float* __restrict__ out) {
    const int wg  = blockIdx.x;
    const int xcd = wg & 7;
    const int pos = wg >> 3;          // 0..95
    const int j   = pos & 15;         // ntile
    const int r   = (pos >> 4) * 8 + xcd;   // record rank 0..47

    const int* rec = recs + r * RSTRIDE;
    const int cat = rec[0];
    const int nb  = rec[1];
    if (nb == 0) return;
    const int n0 = j * BN;

    __shared__ short xs[2][BM * LDK];   // 80 KB
    __shared__ short wt[2][BN * LDK];   // 10 KB

    const int t    = threadIdx.x;
    const int lane = t & 63;
    const int w    = t >> 6;     // wave 0..15
    const int wm   = w >> 1;     // 0..7
    const int wn   = w & 1;      // 0..1
    const int fl   = lane & 15;
    const int kb   = lane >> 4;

    // X staging: wave w stages batch slot w (rows i*8 + (lane>>3), k (lane&7)*4)
    const int  xrow   = lane >> 3;
    const int  xk4    = (lane & 7) * 4;
    const int  xbatch = rec[2 + w];
    const bool xact   = (w < nb);
    const float* xsrc = x + (size_t)(xbatch * TT + xrow) * DIN + xk4;
    short* xd0 = &xs[0][0] + (w * 32 + xrow) * LDK + xk4;
    short* xd1 = &xs[1][0] + (w * 32 + xrow) * LDK + xk4;

    // W staging: threads 0..127 (waves 0,1); 4x4 register transpose
    const bool wact = (t < 128);
    const int  wk4  = (t & 7) * 4;
    const int  wn4  = ((t >> 3) & 15) * 4;
    const float* wsrc = W + (size_t)cat * (DIN * DH) + (size_t)wk4 * DH + n0 + wn4;

    // MFMA active iff this wave's 64-row band intersects real rows
    const bool mact = (wm * 2 < nb);

    float bv[2];
#pragma unroll
    for (int ni = 0; ni < 2; ++ni)
        bv[ni] = bias[cat * DH + n0 + wn * 32 + ni * 16 + fl];

    f32x4 acc[4][2];
#pragma unroll
    for (int i = 0; i < 4; ++i)
#pragma unroll
        for (int q = 0; q < 2; ++q)
            acc[i][q] = (f32x4){0.f, 0.f, 0.f, 0.f};

    const short* ap0 = &xs[0][0] + (wm * 64 + fl) * LDK + kb * 8;
    const short* ap1 = &xs[1][0] + (wm * 64 + fl) * LDK + kb * 8;
    const short* bp0 = &wt[0][0] + (wn * 32 + fl) * LDK + kb * 8;
    const short* bp1 = &wt[1][0] + (wn * 32 + fl) * LDK + kb * 8;

    // prologue: load K-tile 0
    f32x4 xv[4], wv[4];
    if (xact) {
#pragma unroll
        for (int i = 0; i < 4; ++i)
            xv[i] = *(const f32x4*)(xsrc + (size_t)(i * 8) * DIN);
    }
    if (wact) {
#pragma unroll
        for (int i = 0; i < 4; ++i)
            wv[i] = *(const f32x4*)(wsrc + (size_t)i * DH);
    }

    for (int it = 0; it < NITER; it += 2) {
        gemm_step(xv, wv, xd0, &wt[0][0], ap0, bp0, xsrc, wsrc,
                  xact, wact, mact, wn4, wk4, it, acc);
        gemm_step(xv, wv, xd1, &wt[1][0], ap1, bp1, xsrc, wsrc,
                  xact, wact, mact, wn4, wk4, it + 1, acc);
    }

    // --- epilogue: bias + store rows of real batch slots ---
    if (mact) {
#pragma unroll
        for (int mi = 0; mi < 4; ++mi) {
            const int slot = wm * 2 + (mi >> 1);
            if (slot < nb) {
                const int batch = rec[2 + slot];
                const int rb = (mi & 1) * 16 + kb * 4;
#pragma unroll
                for (int jj = 0; jj < 4; ++jj) {
                    const int trow = rb + jj;
                    float* orow = out + (size_t)(batch * TT + trow) * DH + n0 + wn * 32;
#pragma unroll
                    for (int ni = 0; ni < 2; ++ni)
                        orow[ni * 16 + fl] = acc[mi][ni][jj] + bv[ni];
                }
            }
        }
    }
}

extern "C" void kernel_launch(void* const* d_in, const int* in_sizes, int n_in,
                              void* d_out, int out_size, void* d_ws, size_t ws_size,
                              hipStream_t stream) {
    const float* x       = (const float*)d_in[0];
    const int*   cat_ids = (const int*)d_in[1];
    const float* W       = (const float*)d_in[2];
    const float* bias    = (const float*)d_in[3];
    float*       out     = (float*)d_out;
    int*         recs    = (int*)d_ws;

    hipLaunchKernelGGL(cat_setup_kernel, dim3(1), dim3(256), 0, stream,
                       cat_ids, recs);
    // grid: (NRECPAD/8) * NTILES * 8 = 6*16*8 = 768; inactive records exit fast
    hipLaunchKernelGGL(cat_gemm_kernel, dim3((NRECPAD / 8) * NTILES * 8),
                       dim3(1024), 0, stream, x, W, bias, recs, out);
}